// Round 10
// baseline (1857.837 us; speedup 1.0000x reference)
//
#include <hip/hip_runtime.h>
#include <stdint.h>

typedef unsigned int u32;
typedef unsigned short u16;
typedef _Float16 f16;
typedef _Float16 f16x8 __attribute__((ext_vector_type(8)));
typedef _Float16 f16x4 __attribute__((ext_vector_type(4)));
typedef _Float16 f16x2 __attribute__((ext_vector_type(2)));
typedef float f32x4 __attribute__((ext_vector_type(4)));

constexpr int NB = 4096;   // batch
constexpr int NT = 56;     // encoder steps
constexpr int NS = 28;     // decoder steps
constexpr int NH = 126;    // hidden
constexpr int NHP = 128;
constexpr float LOG2E = 1.4426950408889634f;

// decoder LDS row geometry: row 136 f16 = 68 words (%32=4 -> per-t bank rotation),
// per-b stride 56*136+8 = 7624 f16 (%32=4)
constexpr int LROW = 136;
constexpr int LB   = NT * LROW + 8;   // 7624

// workspace offsets (bytes)
constexpr size_t OFF_H    = 0;                    // f32[4096*128] h state (pads 0)
constexpr size_t OFF_ENC  = 2097152;              // f16[4096*56*128] enc_out [b][t][h]
constexpr size_t OFF_UO   = OFF_ENC + 58720256;   // f16[4096*56*128] Uo      [b][t][h]
constexpr size_t OFF_WENC = OFF_UO + 58720256;    // f16[384*160]  enc gates [x20+pad|h128]
constexpr size_t OFF_WDEC = OFF_WENC + 122880;    // f16[384*288]  dec gates [head16+pad|attn128|h128]
constexpr size_t OFF_WL   = OFF_WDEC + 221184;    // f16[128*128]  Wl
constexpr size_t OFF_UW   = OFF_WL + 32768;       // f16[128*128]  U_W

__device__ __forceinline__ float fexp2(float x){ return __builtin_amdgcn_exp2f(x); }
__device__ __forceinline__ float frcp (float x){ return __builtin_amdgcn_rcpf(x); }
__device__ __forceinline__ float sigm (float x){ return frcp(1.f + fexp2(-LOG2E * x)); }
__device__ __forceinline__ float ftanh(float x){ return 1.f - 2.f * frcp(1.f + fexp2(2.f * LOG2E * x)); }

// ---------------- weight repack ----------------
__global__ void k_prep(const float* __restrict__ eWih, const float* __restrict__ eWhh,
                       const float* __restrict__ dWih, const float* __restrict__ dWhh,
                       const float* __restrict__ UW,   const float* __restrict__ Wl,
                       char* __restrict__ ws)
{
  f16* wenc = (f16*)(ws + OFF_WENC);
  f16* wdec = (f16*)(ws + OFF_WDEC);
  f16* wl   = (f16*)(ws + OFF_WL);
  f16* uw   = (f16*)(ws + OFF_UW);
  const int nE = 384 * 160, nD = 384 * 288, nW = 128 * 128;
  const int total = nE + nD + nW + nW;
  for (int i = blockIdx.x * 256 + threadIdx.x; i < total; i += gridDim.x * 256) {
    int idx = i;
    if (idx < nE) {
      const int r = idx / 160, c = idx % 160;
      float v = 0.f;
      if (r < 378) {
        if (c < 20) v = eWih[r * 20 + c];
        else if (c >= 32 && c < 158) v = eWhh[r * 126 + (c - 32)];
      }
      wenc[idx] = (f16)v; continue;
    }
    idx -= nE;
    if (idx < nD) {
      const int r = idx / 288, c = idx % 288;
      float v = 0.f;
      if (r < 378) {
        if (c < 16) v = dWih[r * 142 + c];
        else if (c >= 32 && c < 158) v = dWih[r * 142 + 16 + (c - 32)];
        else if (c >= 160 && c < 286) v = dWhh[r * 126 + (c - 160)];
      }
      wdec[idx] = (f16)v; continue;
    }
    idx -= nD;
    if (idx < nW) {
      const int r = idx >> 7, c = idx & 127;
      wl[idx] = (f16)((r < 126 && c < 126) ? Wl[r * 126 + c] : 0.f);
      continue;
    }
    idx -= nW;
    { const int r = idx >> 7, c = idx & 127;
      uw[idx] = (f16)((r < 126 && c < 126) ? UW[r * 126 + c] : 0.f); }
  }
}

// ---------------- init MLP ----------------
__global__ __launch_bounds__(256) void k_mlp(
    const float* __restrict__ ann, const float* __restrict__ W1, const float* __restrict__ b1,
    const float* __restrict__ W2, const float* __restrict__ b2, float* __restrict__ hstate)
{
  __shared__ float anns[32][33];
  __shared__ float t1s[32][101];
  const int tid = threadIdx.x;
  const int b0 = blockIdx.x * 32;
  for (int i = tid; i < 32 * 30; i += 256)
    anns[i / 30][i % 30] = ann[(b0 + i / 30) * 30 + (i % 30)];
  __syncthreads();
  const int b = tid & 31, rg = tid >> 5;
  for (int m = rg; m < 96; m += 8) {
    float a = b1[m];
    for (int k = 0; k < 30; ++k) a += W1[m * 30 + k] * anns[b][k];
    t1s[b][m] = fmaxf(a, 0.f);
  }
  __syncthreads();
  for (int j = rg; j < NHP; j += 8) {
    float a = 0.f;
    if (j < NH) {
      a = b2[j];
      for (int k = 0; k < 96; ++k) a += W2[j * 96 + k] * t1s[b][k];
    }
    hstate[(b0 + b) * NHP + j] = a;
  }
}

// ---------------- encoder: MFMA, reg-resident weights, M=16, h double-buffered ----------------
__global__ __launch_bounds__(512) void k_enc(
    const float* __restrict__ xenc, const f16* __restrict__ Wenc,
    const f16* __restrict__ Uw,
    const float* __restrict__ bih, const float* __restrict__ bhh,
    const float* __restrict__ Ub,
    float* __restrict__ hstate, f16* __restrict__ encO, f16* __restrict__ uoO)
{
  __shared__ f16 av[16][296];
  const int tid = threadIdx.x;
  const int wid = tid >> 6, l = tid & 63, quad = l >> 4, col = l & 15;
  const int b0 = blockIdx.x * 16;
  const int jb = wid * 16, j = jb + col;
  const bool valid = j < NH;
  const int jc = valid ? j : NH - 1;

  const float br  = bih[jc]        + bhh[jc];
  const float bz  = bih[NH + jc]   + bhh[NH + jc];
  const float bnx = bih[2*NH + jc];
  const float bnh = bhh[2*NH + jc];
  const float ub  = Ub[jc];

  f16x8 rB[5], zB[5], nxB, nhB[4], uB[4];
  {
    const int ko = quad * 8, rr = jb + col;
#pragma unroll
    for (int kt = 0; kt < 5; ++kt) {
      rB[kt] = *(const f16x8*)&Wenc[rr * 160 + kt * 32 + ko];
      zB[kt] = *(const f16x8*)&Wenc[(NH + rr) * 160 + kt * 32 + ko];
    }
    nxB = *(const f16x8*)&Wenc[(2*NH + rr) * 160 + ko];
#pragma unroll
    for (int kt = 0; kt < 4; ++kt) {
      nhB[kt] = *(const f16x8*)&Wenc[(2*NH + rr) * 160 + 32 + kt * 32 + ko];
      uB[kt]  = *(const f16x8*)&Uw[rr * 128 + kt * 32 + ko];
    }
  }

  {
    const int bb = tid >> 5, c4 = (tid & 31) * 4;
    const float4 hv = *(const float4*)&hstate[(b0 + bb) * NHP + c4];
    av[bb][32 + c4]     = (f16)hv.x; av[bb][32 + c4 + 1] = (f16)hv.y;
    av[bb][32 + c4 + 2] = (f16)hv.z; av[bb][32 + c4 + 3] = (f16)hv.w;
  }
  if (tid < 192) { const int bb = tid / 12, p = tid % 12; av[bb][20 + p] = (f16)0.f; }
  __syncthreads();

  const int m = col, ko = quad * 8;
  for (int t = 0; t < NT; ++t) {
    const int hp = 32 + (t & 1) * 128, hq = 32 + ((t + 1) & 1) * 128;
    if (tid < 320) {
      const int bb = tid / 20, e = tid % 20;
      av[bb][e] = (f16)xenc[((size_t)t * NB + b0 + bb) * 20 + e];
    }
    __syncthreads();                       // B1
    f16x8 A[5];
    A[0] = *(const f16x8*)&av[m][ko];
#pragma unroll
    for (int kt = 1; kt < 5; ++kt) A[kt] = *(const f16x8*)&av[m][hp + (kt - 1) * 32 + ko];

    f32x4 Cr = {br, br, br, br}, Cz = {bz, bz, bz, bz};
    f32x4 Cnx = {bnx, bnx, bnx, bnx}, Cnh = {bnh, bnh, bnh, bnh};
#pragma unroll
    for (int kt = 0; kt < 5; ++kt) {
      Cr = __builtin_amdgcn_mfma_f32_16x16x32_f16(A[kt], rB[kt], Cr, 0, 0, 0);
      Cz = __builtin_amdgcn_mfma_f32_16x16x32_f16(A[kt], zB[kt], Cz, 0, 0, 0);
    }
    Cnx = __builtin_amdgcn_mfma_f32_16x16x32_f16(A[0], nxB, Cnx, 0, 0, 0);
#pragma unroll
    for (int kt = 0; kt < 4; ++kt)
      Cnh = __builtin_amdgcn_mfma_f32_16x16x32_f16(A[kt + 1], nhB[kt], Cnh, 0, 0, 0);

    float hv4[4];
#pragma unroll
    for (int c = 0; c < 4; ++c) {
      const int bb = quad * 4 + c;
      const float hold = (float)av[bb][hp + j];
      const float r = sigm(Cr[c]), z = sigm(Cz[c]);
      const float n = ftanh(Cnx[c] + r * Cnh[c]);
      hv4[c] = (1.f - z) * n + z * hold;
    }
#pragma unroll
    for (int c = 0; c < 4; ++c) {
      const int bb = quad * 4 + c;
      const f16 hs = valid ? (f16)hv4[c] : (f16)0.f;
      av[bb][hq + j] = hs;
      encO[((size_t)(b0 + bb) * NT + t) * 128 + j] = hs;
    }
    if (t == NT - 1 && valid) {
#pragma unroll
      for (int c = 0; c < 4; ++c)
        hstate[(b0 + quad * 4 + c) * NHP + j] = hv4[c];
    }
    __syncthreads();                       // B3

    f16x8 Ah[4];
#pragma unroll
    for (int kt = 0; kt < 4; ++kt) Ah[kt] = *(const f16x8*)&av[m][hq + kt * 32 + ko];
    f32x4 Cu = {ub, ub, ub, ub};
#pragma unroll
    for (int kt = 0; kt < 4; ++kt)
      Cu = __builtin_amdgcn_mfma_f32_16x16x32_f16(Ah[kt], uB[kt], Cu, 0, 0, 0);
#pragma unroll
    for (int c = 0; c < 4; ++c)
      uoO[((size_t)(b0 + quad * 4 + c) * NT + t) * 128 + j] = valid ? (f16)Cu[c] : (f16)0.f;
  }
}

// ---------------- decoder: M=4, 1024 threads (16 waves), LDS-resident Uo+enc ----------------
// waves 0-7 and 8-15 both own cols ((wid&7)*16); gate MFMAs computed redundantly
// (MFMA pipe ~8% util - redundancy is free); trans phases p2/p3 split across all 16 waves.
__global__ __launch_bounds__(1024, 4) void k_dec(
    const float* __restrict__ xdec, const float* __restrict__ xenc,
    const f16* __restrict__ Wdec, const f16* __restrict__ WlW,
    const float* __restrict__ bih, const float* __restrict__ bhh,
    const float* __restrict__ Wlb, const float* __restrict__ Vw,
    const float* __restrict__ Vb, const float* __restrict__ how,
    const float* __restrict__ hob, const float* __restrict__ hstate,
    const f16* __restrict__ encO, const f16* __restrict__ uoO,
    float* __restrict__ out)
{
  __shared__ __align__(16) f16 uoL[4 * LB];      // 61.0 KB
  __shared__ __align__(16) f16 encL[4 * LB];     // 61.0 KB
  __shared__ __align__(16) f16 av[5][424];       // row 4 = shared zero row
  __shared__ float WhS[4][132];
  __shared__ float scS[4][68];
  __shared__ __align__(16) f16 hows16[128];
  const int tid = threadIdx.x;
  const int wid = tid >> 6, l = tid & 63, quad = l >> 4, col = l & 15;
  const int b0 = blockIdx.x * 4;
  const int jb = (wid & 7) * 16, j = jb + col;
  const bool valid = j < NH;
  const int jc = valid ? j : NH - 1;

  const float br  = bih[jc]        + bhh[jc];
  const float bz  = bih[NH + jc]   + bhh[NH + jc];
  const float bnx = bih[2*NH + jc];
  const float bnh = bhh[2*NH + jc];
  const float wb  = Wlb[jc];
  const float vb0 = Vb[0], hob0 = hob[0];

  f16x8 rB[9], zB[9], nxB[5], nhB[4], wlB[4];
  {
    const int ko = quad * 8, rr = jb + col;
#pragma unroll
    for (int kt = 0; kt < 9; ++kt) {
      rB[kt] = *(const f16x8*)&Wdec[rr * 288 + kt * 32 + ko];
      zB[kt] = *(const f16x8*)&Wdec[(NH + rr) * 288 + kt * 32 + ko];
    }
#pragma unroll
    for (int kt = 0; kt < 5; ++kt)
      nxB[kt] = *(const f16x8*)&Wdec[(2*NH + rr) * 288 + kt * 32 + ko];
#pragma unroll
    for (int kt = 0; kt < 4; ++kt) {
      nhB[kt] = *(const f16x8*)&Wdec[(2*NH + rr) * 288 + 160 + kt * 32 + ko];
      wlB[kt] = *(const f16x8*)&WlW[rr * 128 + kt * 32 + ko];
    }
  }

  const int g = tid >> 3, sub = tid & 7;
  float vreg[16];
#pragma unroll
  for (int i = 0; i < 16; ++i) {
    const int jj = sub * 16 + i;
    vreg[i] = (jj < NH) ? Vw[jj] : 0.f;
  }
  if (tid >= 256 && tid < 384) {
    const int q = tid - 256; hows16[q] = (f16)((q < NH) ? how[q] : 0.f);
  }
  for (int i = tid; i < 5 * 424; i += 1024) av[i / 424][i % 424] = (f16)0.f;
  {
    const size_t gb = (size_t)b0 * NT * 128;
    for (int i = tid; i < 4 * NT * 16; i += 1024) {
      const int ch = i & 15, btr = i >> 4;
      const int bb = btr / NT, tt = btr % NT;
      const int dst = bb * LB + tt * LROW + ch * 8;
      const size_t src = gb + (size_t)btr * 128 + ch * 8;
      *(f16x8*)&uoL [dst] = *(const f16x8*)&uoO [src];
      *(f16x8*)&encL[dst] = *(const f16x8*)&encO[src];
    }
  }
  __syncthreads();
  if (tid < 128) {   // h0 rows 0..3 into parity-0 region [160..288)
    const int bb = tid >> 5, c4 = (tid & 31) * 4;
    const float4 hv = *(const float4*)&hstate[(b0 + bb) * NHP + c4];
    av[bb][160 + c4]     = (f16)hv.x; av[bb][160 + c4 + 1] = (f16)hv.y;
    av[bb][160 + c4 + 2] = (f16)hv.z; av[bb][160 + c4 + 3] = (f16)hv.w;
  }
  if (tid < 4) av[tid][0] = (f16)xenc[((size_t)(NT - 1) * NB + b0 + tid) * 20];  // gt0
  __syncthreads();

  const int m = col, ko = quad * 8;
  const int arow = (m < 4) ? m : 4;
  // p3 mapping: pb = batch, pth = t-quarter (partners tid^4, tid^8), pjp*2 = h-col
  const int pb = tid & 3, pth = (tid >> 2) & 3, pjp = tid >> 4;

  for (int s = 0; s < NS; ++s) {
    const int hp = 160 + (s & 1) * 128, hq = 160 + ((s + 1) & 1) * 128;

    // p1: Wh = h @ Wl^T + Wlb (waves 0-7); waves 8-15 stage dec_x
    if (wid < 8) {
      f16x8 Ah[4];
#pragma unroll
      for (int kt = 0; kt < 4; ++kt) Ah[kt] = *(const f16x8*)&av[arow][hp + kt * 32 + ko];
      f32x4 Cw = {wb, wb, wb, wb};
#pragma unroll
      for (int kt = 0; kt < 4; ++kt)
        Cw = __builtin_amdgcn_mfma_f32_16x16x32_f16(Ah[kt], wlB[kt], Cw, 0, 0, 0);
      if (quad == 0) {
#pragma unroll
        for (int c = 0; c < 4; ++c) WhS[c][j] = Cw[c];
      }
    } else if (tid - 512 < 60) {
      const int q = tid - 512, bb = q / 15, e = q % 15;
      av[bb][1 + e] = (f16)xdec[((size_t)s * NB + b0 + bb) * 15 + e];
    }
    __syncthreads();  // B1

    // p2: scores; 128 groups = 4b x 32 t-base; 2 rounds
    {
      const int sbb = g & 3, tb = g >> 2;
      float wr[16];
#pragma unroll
      for (int i = 0; i < 4; ++i)
        *(float4*)&wr[i * 4] = *(const float4*)&WhS[sbb][sub * 16 + i * 4];
      const f16* up0 = &uoL[sbb * LB + sub * 16];
#pragma unroll
      for (int rd = 0; rd < 2; ++rd) {
        const int t = rd * 32 + tb;
        if (t < NT) {
          const f16* up = up0 + t * LROW;
          const f16x8 q0 = *(const f16x8*)&up[0];
          const f16x8 q1 = *(const f16x8*)&up[8];
          float acc = 0.f;
#pragma unroll
          for (int i = 0; i < 8; ++i) acc += ftanh((float)q0[i] + wr[i]) * vreg[i];
#pragma unroll
          for (int i = 0; i < 8; ++i) acc += ftanh((float)q1[i] + wr[8 + i]) * vreg[8 + i];
          acc += __shfl_xor(acc, 1, 64);
          acc += __shfl_xor(acc, 2, 64);
          acc += __shfl_xor(acc, 4, 64);
          if (sub == 0) scS[sbb][t] = acc + vb0;
        }
      }
    }
    __syncthreads();  // B2

    // p3: fused softmax + attn (scores bounded => no max subtraction).
    // 1024 threads: (pb, j-pair, t-quarter of 14); combine via shfl_xor(4), shfl_xor(8)
    {
      const int j0 = pjp * 2;
      const f16* er = &encL[pb * LB + j0];
      const float* scp = &scS[pb][pth * 14];
      const int tbase = pth * 14;
      float Z = 0.f, a0 = 0.f, a1 = 0.f;
#pragma unroll
      for (int i2 = 0; i2 < 14; i2 += 2) {
        const float2 scv = *(const float2*)&scp[i2];
        const float e0 = fexp2(LOG2E * scv.x);
        const float e1 = fexp2(LOG2E * scv.y);
        Z += e0 + e1;
        const f16x2 v0 = *(const f16x2*)&er[(tbase + i2    ) * LROW];
        const f16x2 v1 = *(const f16x2*)&er[(tbase + i2 + 1) * LROW];
        a0 += e0 * (float)v0[0] + e1 * (float)v1[0];
        a1 += e0 * (float)v0[1] + e1 * (float)v1[1];
      }
      a0 += __shfl_xor(a0, 4, 64);  a1 += __shfl_xor(a1, 4, 64);  Z += __shfl_xor(Z, 4, 64);
      a0 += __shfl_xor(a0, 8, 64);  a1 += __shfl_xor(a1, 8, 64);  Z += __shfl_xor(Z, 8, 64);
      if (pth == 0) {
        const float inv = frcp(Z);
        f16x2 st; st[0] = (f16)(a0 * inv); st[1] = (f16)(a1 * inv);
        *(f16x2*)&av[pb][32 + j0] = st;
      }
    }
    __syncthreads();  // B3

    // p4: GRU gates (MFMA, redundant on both wave-halves) + state update
    {
      f16x8 A[9];
#pragma unroll
      for (int kt = 0; kt < 5; ++kt) A[kt] = *(const f16x8*)&av[arow][kt * 32 + ko];
#pragma unroll
      for (int kt = 5; kt < 9; ++kt) A[kt] = *(const f16x8*)&av[arow][hp + (kt - 5) * 32 + ko];
      f32x4 Cr = {br, br, br, br}, Cz = {bz, bz, bz, bz};
      f32x4 Cnx = {bnx, bnx, bnx, bnx}, Cnh = {bnh, bnh, bnh, bnh};
#pragma unroll
      for (int kt = 0; kt < 9; ++kt) {
        Cr = __builtin_amdgcn_mfma_f32_16x16x32_f16(A[kt], rB[kt], Cr, 0, 0, 0);
        Cz = __builtin_amdgcn_mfma_f32_16x16x32_f16(A[kt], zB[kt], Cz, 0, 0, 0);
      }
#pragma unroll
      for (int kt = 0; kt < 5; ++kt)
        Cnx = __builtin_amdgcn_mfma_f32_16x16x32_f16(A[kt], nxB[kt], Cnx, 0, 0, 0);
#pragma unroll
      for (int kt = 0; kt < 4; ++kt)
        Cnh = __builtin_amdgcn_mfma_f32_16x16x32_f16(A[kt + 5], nhB[kt], Cnh, 0, 0, 0);
      if (quad == 0 && wid < 8) {
#pragma unroll
        for (int c = 0; c < 4; ++c) {
          const float hold = (float)av[c][hp + j];
          const float r = sigm(Cr[c]), z = sigm(Cz[c]);
          const float n = ftanh(Cnx[c] + r * Cnh[c]);
          const float h2 = (1.f - z) * n + z * hold;
          if (valid) av[c][hq + j] = (f16)h2;
        }
      }
    }
    __syncthreads();  // B4

    // p5: out = h' . h2o + b via n=1 MFMA on wave 0; lane 0 writes outputs + next prev
    if (wid == 0) {
      f16x8 Ah2[4], hB[4];
      const f16x8 zz = {};
#pragma unroll
      for (int kt = 0; kt < 4; ++kt) {
        Ah2[kt] = *(const f16x8*)&av[arow][hq + kt * 32 + ko];
        hB[kt] = (col == 0) ? *(const f16x8*)&hows16[kt * 32 + ko] : zz;
      }
      f32x4 Co = {0.f, 0.f, 0.f, 0.f};
#pragma unroll
      for (int kt = 0; kt < 4; ++kt)
        Co = __builtin_amdgcn_mfma_f32_16x16x32_f16(Ah2[kt], hB[kt], Co, 0, 0, 0);
      if (l == 0) {
#pragma unroll
        for (int c = 0; c < 4; ++c) {
          const float o = Co[c] + hob0;
          out[(size_t)s * NB + b0 + c] = o;
          av[c][0] = (f16)o;           // next step's prev; ordered by B1..B3 before p4
        }
      }
    }
  }
}

extern "C" void kernel_launch(void* const* d_in, const int* in_sizes, int n_in,
                              void* d_out, int out_size, void* d_ws, size_t ws_size,
                              hipStream_t stream)
{
  const float* ann   = (const float*)d_in[0];
  const float* xenc  = (const float*)d_in[1];
  const float* xdec  = (const float*)d_in[2];
  const float* W1    = (const float*)d_in[3];
  const float* b1    = (const float*)d_in[4];
  const float* W2    = (const float*)d_in[5];
  const float* b2    = (const float*)d_in[6];
  const float* eWih  = (const float*)d_in[7];
  const float* eWhh  = (const float*)d_in[8];
  const float* ebih  = (const float*)d_in[9];
  const float* ebhh  = (const float*)d_in[10];
  const float* dWih  = (const float*)d_in[11];
  const float* dWhh  = (const float*)d_in[12];
  const float* dbih  = (const float*)d_in[13];
  const float* dbhh  = (const float*)d_in[14];
  const float* UW    = (const float*)d_in[15];
  const float* Ubias = (const float*)d_in[16];
  const float* Wl    = (const float*)d_in[17];
  const float* Wlb   = (const float*)d_in[18];
  const float* Vw    = (const float*)d_in[19];
  const float* Vb    = (const float*)d_in[20];
  const float* how   = (const float*)d_in[21];
  const float* hob   = (const float*)d_in[22];

  char* ws = (char*)d_ws;
  float* hstate = (float*)(ws + OFF_H);
  f16*   encB   = (f16*)(ws + OFF_ENC);
  f16*   uoB    = (f16*)(ws + OFF_UO);
  const f16* pWenc = (const f16*)(ws + OFF_WENC);
  const f16* pWdec = (const f16*)(ws + OFF_WDEC);
  const f16* pWl   = (const f16*)(ws + OFF_WL);
  const f16* pUW   = (const f16*)(ws + OFF_UW);

  k_prep<<<200, 256, 0, stream>>>(eWih, eWhh, dWih, dWhh, UW, Wl, ws);
  k_mlp <<<128, 256, 0, stream>>>(ann, W1, b1, W2, b2, hstate);
  k_enc <<<NB / 16, 512, 0, stream>>>(xenc, pWenc, pUW, ebih, ebhh, Ubias,
                                      hstate, encB, uoB);
  k_dec <<<NB / 4, 1024, 0, stream>>>(xdec, xenc, pWdec, pWl, dbih, dbhh,
                                      Wlb, Vw, Vb, how, hob, hstate,
                                      encB, uoB, (float*)d_out);
}

// Round 11
// 1141.404 us; speedup vs baseline: 1.6277x; 1.6277x over previous
//
#include <hip/hip_runtime.h>
#include <stdint.h>

typedef unsigned int u32;
typedef unsigned short u16;
typedef _Float16 f16;
typedef _Float16 f16x8 __attribute__((ext_vector_type(8)));
typedef _Float16 f16x4 __attribute__((ext_vector_type(4)));
typedef _Float16 f16x2 __attribute__((ext_vector_type(2)));
typedef float f32x4 __attribute__((ext_vector_type(4)));

constexpr int NB = 4096;   // batch
constexpr int NT = 56;     // encoder steps
constexpr int NS = 28;     // decoder steps
constexpr int NH = 126;    // hidden
constexpr int NHP = 128;
constexpr float LOG2E = 1.4426950408889634f;

// decoder LDS row geometry: row 136 elems (%32 words = 4 -> per-t bank rotation)
constexpr int LROW = 136;
constexpr int LB   = NT * LROW + 8;   // 7624

// workspace offsets (bytes)
constexpr size_t OFF_H    = 0;                    // f32[4096*128] h state (pads 0)
constexpr size_t OFF_ENC  = 2097152;              // f16[4096*56*128] enc_out [b][t][h]
constexpr size_t OFF_UO   = OFF_ENC + 58720256;   // bf16[4096*56*128] EU=e^(2*Uo) [b][t][h]
constexpr size_t OFF_WENC = OFF_UO + 58720256;    // f16[384*160]  enc gates [x20+pad|h128]
constexpr size_t OFF_WDEC = OFF_WENC + 122880;    // f16[384*288]  dec gates [head16+pad|attn128|h128]
constexpr size_t OFF_WL   = OFF_WDEC + 221184;    // f16[128*128]  Wl
constexpr size_t OFF_UW   = OFF_WL + 32768;       // f16[128*128]  U_W

__device__ __forceinline__ float fexp2(float x){ return __builtin_amdgcn_exp2f(x); }
__device__ __forceinline__ float frcp (float x){ return __builtin_amdgcn_rcpf(x); }
__device__ __forceinline__ float sigm (float x){ return frcp(1.f + fexp2(-LOG2E * x)); }
__device__ __forceinline__ float ftanh(float x){ return 1.f - 2.f * frcp(1.f + fexp2(2.f * LOG2E * x)); }
__device__ __forceinline__ float asf(u32 u){ union { u32 i; float f; } v; v.i = u; return v.f; }
__device__ __forceinline__ u16 tobf(float f){ union { float f; u32 i; } v; v.f = f;
  return (u16)((v.i + 0x7fffu + ((v.i >> 16) & 1u)) >> 16); }

// ---------------- weight repack ----------------
__global__ void k_prep(const float* __restrict__ eWih, const float* __restrict__ eWhh,
                       const float* __restrict__ dWih, const float* __restrict__ dWhh,
                       const float* __restrict__ UW,   const float* __restrict__ Wl,
                       char* __restrict__ ws)
{
  f16* wenc = (f16*)(ws + OFF_WENC);
  f16* wdec = (f16*)(ws + OFF_WDEC);
  f16* wl   = (f16*)(ws + OFF_WL);
  f16* uw   = (f16*)(ws + OFF_UW);
  const int nE = 384 * 160, nD = 384 * 288, nW = 128 * 128;
  const int total = nE + nD + nW + nW;
  for (int i = blockIdx.x * 256 + threadIdx.x; i < total; i += gridDim.x * 256) {
    int idx = i;
    if (idx < nE) {
      const int r = idx / 160, c = idx % 160;
      float v = 0.f;
      if (r < 378) {
        if (c < 20) v = eWih[r * 20 + c];
        else if (c >= 32 && c < 158) v = eWhh[r * 126 + (c - 32)];
      }
      wenc[idx] = (f16)v; continue;
    }
    idx -= nE;
    if (idx < nD) {
      const int r = idx / 288, c = idx % 288;
      float v = 0.f;
      if (r < 378) {
        if (c < 16) v = dWih[r * 142 + c];
        else if (c >= 32 && c < 158) v = dWih[r * 142 + 16 + (c - 32)];
        else if (c >= 160 && c < 286) v = dWhh[r * 126 + (c - 160)];
      }
      wdec[idx] = (f16)v; continue;
    }
    idx -= nD;
    if (idx < nW) {
      const int r = idx >> 7, c = idx & 127;
      wl[idx] = (f16)((r < 126 && c < 126) ? Wl[r * 126 + c] : 0.f);
      continue;
    }
    idx -= nW;
    { const int r = idx >> 7, c = idx & 127;
      uw[idx] = (f16)((r < 126 && c < 126) ? UW[r * 126 + c] : 0.f); }
  }
}

// ---------------- init MLP ----------------
__global__ __launch_bounds__(256) void k_mlp(
    const float* __restrict__ ann, const float* __restrict__ W1, const float* __restrict__ b1,
    const float* __restrict__ W2, const float* __restrict__ b2, float* __restrict__ hstate)
{
  __shared__ float anns[32][33];
  __shared__ float t1s[32][101];
  const int tid = threadIdx.x;
  const int b0 = blockIdx.x * 32;
  for (int i = tid; i < 32 * 30; i += 256)
    anns[i / 30][i % 30] = ann[(b0 + i / 30) * 30 + (i % 30)];
  __syncthreads();
  const int b = tid & 31, rg = tid >> 5;
  for (int m = rg; m < 96; m += 8) {
    float a = b1[m];
    for (int k = 0; k < 30; ++k) a += W1[m * 30 + k] * anns[b][k];
    t1s[b][m] = fmaxf(a, 0.f);
  }
  __syncthreads();
  for (int j = rg; j < NHP; j += 8) {
    float a = 0.f;
    if (j < NH) {
      a = b2[j];
      for (int k = 0; k < 96; ++k) a += W2[j * 96 + k] * t1s[b][k];
    }
    hstate[(b0 + b) * NHP + j] = a;
  }
}

// ---------------- encoder: MFMA, reg-resident weights, M=8 b/block, 512 blocks ----------------
// 2 blocks/CU co-resident (VGPR ~76, LDS ~9.5KB) to overlap barrier stalls.
// av rows 8..15 zeroed once (dead MFMA M-rows).  Stores EU = e^(2*Uo) in bf16.
__global__ __launch_bounds__(512) void k_enc(
    const float* __restrict__ xenc, const f16* __restrict__ Wenc,
    const f16* __restrict__ Uw,
    const float* __restrict__ bih, const float* __restrict__ bhh,
    const float* __restrict__ Ub,
    float* __restrict__ hstate, f16* __restrict__ encO, u16* __restrict__ uoO)
{
  __shared__ f16 av[16][296];   // [b][ x20+pad12 | h_p0 128 | h_p1 128 | pad ]
  const int tid = threadIdx.x;
  const int wid = tid >> 6, l = tid & 63, quad = l >> 4, col = l & 15;
  const int b0 = blockIdx.x * 8;
  const int jb = wid * 16, j = jb + col;
  const bool valid = j < NH;
  const int jc = valid ? j : NH - 1;

  const float br  = bih[jc]        + bhh[jc];
  const float bz  = bih[NH + jc]   + bhh[NH + jc];
  const float bnx = bih[2*NH + jc];
  const float bnh = bhh[2*NH + jc];
  const float ub  = Ub[jc];

  f16x8 rB[5], zB[5], nxB, nhB[4], uB[4];
  {
    const int ko = quad * 8, rr = jb + col;
#pragma unroll
    for (int kt = 0; kt < 5; ++kt) {
      rB[kt] = *(const f16x8*)&Wenc[rr * 160 + kt * 32 + ko];
      zB[kt] = *(const f16x8*)&Wenc[(NH + rr) * 160 + kt * 32 + ko];
    }
    nxB = *(const f16x8*)&Wenc[(2*NH + rr) * 160 + ko];
#pragma unroll
    for (int kt = 0; kt < 4; ++kt) {
      nhB[kt] = *(const f16x8*)&Wenc[(2*NH + rr) * 160 + 32 + kt * 32 + ko];
      uB[kt]  = *(const f16x8*)&Uw[rr * 128 + kt * 32 + ko];
    }
  }

  if (tid < 256) {   // h0 rows 0..7 into parity-0
    const int bb = tid >> 5, c4 = (tid & 31) * 4;
    const float4 hv = *(const float4*)&hstate[(b0 + bb) * NHP + c4];
    av[bb][32 + c4]     = (f16)hv.x; av[bb][32 + c4 + 1] = (f16)hv.y;
    av[bb][32 + c4 + 2] = (f16)hv.z; av[bb][32 + c4 + 3] = (f16)hv.w;
  }
  if (tid < 96) { const int bb = tid / 12, p = tid % 12; av[bb][20 + p] = (f16)0.f; }
  for (int i = tid; i < 8 * 296; i += 512) av[8 + i / 296][i % 296] = (f16)0.f;
  __syncthreads();

  const int m = col, ko = quad * 8;
  for (int t = 0; t < NT; ++t) {
    const int hp = 32 + (t & 1) * 128, hq = 32 + ((t + 1) & 1) * 128;
    if (tid < 160) {
      const int bb = tid / 20, e = tid % 20;
      av[bb][e] = (f16)xenc[((size_t)t * NB + b0 + bb) * 20 + e];
    }
    __syncthreads();                       // B1
    f16x8 A[5];
    A[0] = *(const f16x8*)&av[m][ko];
#pragma unroll
    for (int kt = 1; kt < 5; ++kt) A[kt] = *(const f16x8*)&av[m][hp + (kt - 1) * 32 + ko];

    f32x4 Cr = {br, br, br, br}, Cz = {bz, bz, bz, bz};
    f32x4 Cnx = {bnx, bnx, bnx, bnx}, Cnh = {bnh, bnh, bnh, bnh};
#pragma unroll
    for (int kt = 0; kt < 5; ++kt) {
      Cr = __builtin_amdgcn_mfma_f32_16x16x32_f16(A[kt], rB[kt], Cr, 0, 0, 0);
      Cz = __builtin_amdgcn_mfma_f32_16x16x32_f16(A[kt], zB[kt], Cz, 0, 0, 0);
    }
    Cnx = __builtin_amdgcn_mfma_f32_16x16x32_f16(A[0], nxB, Cnx, 0, 0, 0);
#pragma unroll
    for (int kt = 0; kt < 4; ++kt)
      Cnh = __builtin_amdgcn_mfma_f32_16x16x32_f16(A[kt + 1], nhB[kt], Cnh, 0, 0, 0);

    float hv4[4];
#pragma unroll
    for (int c = 0; c < 4; ++c) {
      const int bb = quad * 4 + c;
      const float hold = (float)av[bb][hp + j];
      const float r = sigm(Cr[c]), z = sigm(Cz[c]);
      const float n = ftanh(Cnx[c] + r * Cnh[c]);
      hv4[c] = (1.f - z) * n + z * hold;
    }
#pragma unroll
    for (int c = 0; c < 4; ++c) {
      const int bb = quad * 4 + c;
      if (bb < 8) {
        const f16 hs = valid ? (f16)hv4[c] : (f16)0.f;
        av[bb][hq + j] = hs;
        encO[((size_t)(b0 + bb) * NT + t) * 128 + j] = hs;
      }
    }
    if (t == NT - 1 && valid) {
#pragma unroll
      for (int c = 0; c < 4; ++c)
        if (quad * 4 + c < 8) hstate[(b0 + quad * 4 + c) * NHP + j] = hv4[c];
    }
    __syncthreads();                       // B2

    f16x8 Ah[4];
#pragma unroll
    for (int kt = 0; kt < 4; ++kt) Ah[kt] = *(const f16x8*)&av[m][hq + kt * 32 + ko];
    f32x4 Cu = {ub, ub, ub, ub};
#pragma unroll
    for (int kt = 0; kt < 4; ++kt)
      Cu = __builtin_amdgcn_mfma_f32_16x16x32_f16(Ah[kt], uB[kt], Cu, 0, 0, 0);
#pragma unroll
    for (int c = 0; c < 4; ++c)
      if (quad * 4 + c < 8) {
        const u16 eu = tobf(fexp2(2.f * LOG2E * Cu[c]));   // EU = e^(2*Uo)
        uoO[((size_t)(b0 + quad * 4 + c) * NT + t) * 128 + j] = valid ? eu : (u16)0;
      }
  }
}

// ---------------- decoder: M=4, 768 threads (12 waves), LDS-resident EU+enc ----------------
// p2 uses all 12 waves; p1/p4 MFMA on waves 0-7; p3 on threads 0-511; p5 on wave 0.
// tanh(Uo+Wh) = 1 - 2/(1 + EU*EW):  1 unpack + 1 fma + 1 rcp + 1 fma per element.
__global__ __launch_bounds__(768) void k_dec(
    const float* __restrict__ xdec, const float* __restrict__ xenc,
    const f16* __restrict__ Wdec, const f16* __restrict__ WlW,
    const float* __restrict__ bih, const float* __restrict__ bhh,
    const float* __restrict__ Wlb, const float* __restrict__ Vw,
    const float* __restrict__ Vb, const float* __restrict__ how,
    const float* __restrict__ hob, const float* __restrict__ hstate,
    const f16* __restrict__ encO, const u16* __restrict__ uoO,
    float* __restrict__ out)
{
  __shared__ __align__(16) u16 uoL[4 * LB];      // EU bf16, 61.0 KB
  __shared__ __align__(16) f16 encL[4 * LB];     // 61.0 KB
  __shared__ __align__(16) f16 av[5][424];       // [b][head16+pad16|attn128|h_p0|h_p1|pad]; row4 = 0
  __shared__ float EWS[4][132];                  // e^(2*Wh) per step
  __shared__ float scS[4][68];
  __shared__ __align__(16) f16 hows16[128];
  const int tid = threadIdx.x;
  const int wid = tid >> 6, l = tid & 63, quad = l >> 4, col = l & 15;
  const int b0 = blockIdx.x * 4;
  const int jb = (wid & 7) * 16, j = jb + col;
  const bool valid = j < NH;
  const int jc = valid ? j : NH - 1;

  const float br  = bih[jc]        + bhh[jc];
  const float bz  = bih[NH + jc]   + bhh[NH + jc];
  const float bnx = bih[2*NH + jc];
  const float bnh = bhh[2*NH + jc];
  const float wb  = Wlb[jc];
  const float vb0 = Vb[0], hob0 = hob[0];

  f16x8 rB[9], zB[9], nxB[5], nhB[4], wlB[4];
  if (wid < 8) {
    const int ko = quad * 8, rr = jb + col;
#pragma unroll
    for (int kt = 0; kt < 9; ++kt) {
      rB[kt] = *(const f16x8*)&Wdec[rr * 288 + kt * 32 + ko];
      zB[kt] = *(const f16x8*)&Wdec[(NH + rr) * 288 + kt * 32 + ko];
    }
#pragma unroll
    for (int kt = 0; kt < 5; ++kt)
      nxB[kt] = *(const f16x8*)&Wdec[(2*NH + rr) * 288 + kt * 32 + ko];
#pragma unroll
    for (int kt = 0; kt < 4; ++kt) {
      nhB[kt] = *(const f16x8*)&Wdec[(2*NH + rr) * 288 + 160 + kt * 32 + ko];
      wlB[kt] = *(const f16x8*)&WlW[rr * 128 + kt * 32 + ko];
    }
  }

  const int g = tid >> 3, sub = tid & 7;       // g 0..95
  float n2v[16], svsum = 0.f;
#pragma unroll
  for (int i = 0; i < 16; ++i) {
    const int jj = sub * 16 + i;
    const float v = (jj < NH) ? Vw[jj] : 0.f;
    n2v[i] = -2.f * v;
    svsum += v;
  }
  if (tid >= 256 && tid < 384) {
    const int q = tid - 256; hows16[q] = (f16)((q < NH) ? how[q] : 0.f);
  }
  for (int i = tid; i < 5 * 424; i += 768) av[i / 424][i % 424] = (f16)0.f;
  if (tid < 24) EWS[tid / 6][126 + tid % 6] = 0.f;   // pad cols (LDS garbage may be NaN)
  {
    const size_t gb = (size_t)b0 * NT * 128;
    for (int i = tid; i < 4 * NT * 16; i += 768) {
      const int ch = i & 15, btr = i >> 4;
      const int bb = btr / NT, tt = btr % NT;
      const int dst = bb * LB + tt * LROW + ch * 8;
      const size_t src = gb + (size_t)btr * 128 + ch * 8;
      *(f16x8*)&uoL [dst] = *(const f16x8*)&uoO [src];
      *(f16x8*)&encL[dst] = *(const f16x8*)&encO[src];
    }
  }
  __syncthreads();
  if (tid < 128) {   // h0 rows 0..3 into parity-0 [160..288)
    const int bb = tid >> 5, c4 = (tid & 31) * 4;
    const float4 hv = *(const float4*)&hstate[(b0 + bb) * NHP + c4];
    av[bb][160 + c4]     = (f16)hv.x; av[bb][160 + c4 + 1] = (f16)hv.y;
    av[bb][160 + c4 + 2] = (f16)hv.z; av[bb][160 + c4 + 3] = (f16)hv.w;
  }
  if (tid < 4) av[tid][0] = (f16)xenc[((size_t)(NT - 1) * NB + b0 + tid) * 20];  // gt0
  __syncthreads();

  const int m = col, ko = quad * 8;
  const int arow = (m < 4) ? m : 4;
  const int pb = tid & 3, pth = (tid >> 2) & 1, pjp = tid >> 3;   // p3 map (tid<512)

  for (int s = 0; s < NS; ++s) {
    const int hp = 160 + (s & 1) * 128, hq = 160 + ((s + 1) & 1) * 128;

    // p1: Wh -> EW = e^(2*Wh) (waves 0-7); waves 8-11 stage dec_x
    if (wid < 8) {
      f16x8 Ah[4];
#pragma unroll
      for (int kt = 0; kt < 4; ++kt) Ah[kt] = *(const f16x8*)&av[arow][hp + kt * 32 + ko];
      f32x4 Cw = {wb, wb, wb, wb};
#pragma unroll
      for (int kt = 0; kt < 4; ++kt)
        Cw = __builtin_amdgcn_mfma_f32_16x16x32_f16(Ah[kt], wlB[kt], Cw, 0, 0, 0);
      if (quad == 0 && valid) {
#pragma unroll
        for (int c = 0; c < 4; ++c) EWS[c][j] = fexp2(2.f * LOG2E * Cw[c]);
      }
    } else if (tid - 512 < 60) {
      const int q = tid - 512, bb = q / 15, e = q % 15;
      av[bb][1 + e] = (f16)xdec[((size_t)s * NB + b0 + bb) * 15 + e];
    }
    __syncthreads();  // B1

    // p2: scores via 1 - 2/(1+EU*EW); 96 groups = 4b x 24 t-base, 3 rounds
    {
      const int sbb = g & 3, tb = g >> 2;
      float ew[16];
#pragma unroll
      for (int i = 0; i < 4; ++i)
        *(float4*)&ew[i * 4] = *(const float4*)&EWS[sbb][sub * 16 + i * 4];
      const u16* up0 = &uoL[sbb * LB + sub * 16];
#pragma unroll
      for (int rd = 0; rd < 3; ++rd) {
        const int t = rd * 24 + tb;
        if (t < NT) {
          const u16* up = up0 + t * LROW;
          const uint4 q0 = *(const uint4*)&up[0];
          const uint4 q1 = *(const uint4*)&up[8];
          float acc = svsum;
          const u32 ws[8] = {q0.x, q0.y, q0.z, q0.w, q1.x, q1.y, q1.z, q1.w};
#pragma unroll
          for (int k = 0; k < 8; ++k) {
            const float p0 = fmaf(asf(ws[k] << 16),          ew[2 * k],     1.f);
            const float p1 = fmaf(asf(ws[k] & 0xffff0000u),  ew[2 * k + 1], 1.f);
            acc = fmaf(n2v[2 * k],     frcp(p0), acc);
            acc = fmaf(n2v[2 * k + 1], frcp(p1), acc);
          }
          acc += __shfl_xor(acc, 1, 64);
          acc += __shfl_xor(acc, 2, 64);
          acc += __shfl_xor(acc, 4, 64);
          if (sub == 0) scS[sbb][t] = acc + vb0;
        }
      }
    }
    __syncthreads();  // B2

    // p3: fused softmax + attn (threads 0-511); scores bounded -> no max subtraction
    if (tid < 512) {
      const int j0 = pjp * 2;
      const f16* er = &encL[pb * LB + j0];
      const float* scp = &scS[pb][pth * 28];
      const int tbase = pth * 28;
      float Z = 0.f, a0 = 0.f, a1 = 0.f;
#pragma unroll
      for (int i2 = 0; i2 < 28; i2 += 2) {
        const float2 scv = *(const float2*)&scp[i2];
        const float e0 = fexp2(LOG2E * scv.x);
        const float e1 = fexp2(LOG2E * scv.y);
        Z += e0 + e1;
        const f16x2 v0 = *(const f16x2*)&er[(tbase + i2    ) * LROW];
        const f16x2 v1 = *(const f16x2*)&er[(tbase + i2 + 1) * LROW];
        a0 += e0 * (float)v0[0] + e1 * (float)v1[0];
        a1 += e0 * (float)v0[1] + e1 * (float)v1[1];
      }
      a0 += __shfl_xor(a0, 4, 64);
      a1 += __shfl_xor(a1, 4, 64);
      Z  += __shfl_xor(Z, 4, 64);
      if (pth == 0) {
        const float inv = frcp(Z);
        f16x2 st; st[0] = (f16)(a0 * inv); st[1] = (f16)(a1 * inv);
        *(f16x2*)&av[pb][32 + j0] = st;
      }
    }
    __syncthreads();  // B3

    // p4: GRU gates (MFMA, waves 0-7) + state update into other parity
    if (wid < 8) {
      f16x8 A[9];
#pragma unroll
      for (int kt = 0; kt < 5; ++kt) A[kt] = *(const f16x8*)&av[arow][kt * 32 + ko];
#pragma unroll
      for (int kt = 5; kt < 9; ++kt) A[kt] = *(const f16x8*)&av[arow][hp + (kt - 5) * 32 + ko];
      f32x4 Cr = {br, br, br, br}, Cz = {bz, bz, bz, bz};
      f32x4 Cnx = {bnx, bnx, bnx, bnx}, Cnh = {bnh, bnh, bnh, bnh};
#pragma unroll
      for (int kt = 0; kt < 9; ++kt) {
        Cr = __builtin_amdgcn_mfma_f32_16x16x32_f16(A[kt], rB[kt], Cr, 0, 0, 0);
        Cz = __builtin_amdgcn_mfma_f32_16x16x32_f16(A[kt], zB[kt], Cz, 0, 0, 0);
      }
#pragma unroll
      for (int kt = 0; kt < 5; ++kt)
        Cnx = __builtin_amdgcn_mfma_f32_16x16x32_f16(A[kt], nxB[kt], Cnx, 0, 0, 0);
#pragma unroll
      for (int kt = 0; kt < 4; ++kt)
        Cnh = __builtin_amdgcn_mfma_f32_16x16x32_f16(A[kt + 5], nhB[kt], Cnh, 0, 0, 0);
      if (quad == 0) {
#pragma unroll
        for (int c = 0; c < 4; ++c) {
          const float hold = (float)av[c][hp + j];
          const float r = sigm(Cr[c]), z = sigm(Cz[c]);
          const float n = ftanh(Cnx[c] + r * Cnh[c]);
          const float h2 = (1.f - z) * n + z * hold;
          if (valid) av[c][hq + j] = (f16)h2;
        }
      }
    }
    __syncthreads();  // B4

    // p5: out = h' . h2o + b via n=1 MFMA on wave 0
    if (wid == 0) {
      f16x8 Ah2[4], hB[4];
      const f16x8 zz = {};
#pragma unroll
      for (int kt = 0; kt < 4; ++kt) {
        Ah2[kt] = *(const f16x8*)&av[arow][hq + kt * 32 + ko];
        hB[kt] = (col == 0) ? *(const f16x8*)&hows16[kt * 32 + ko] : zz;
      }
      f32x4 Co = {0.f, 0.f, 0.f, 0.f};
#pragma unroll
      for (int kt = 0; kt < 4; ++kt)
        Co = __builtin_amdgcn_mfma_f32_16x16x32_f16(Ah2[kt], hB[kt], Co, 0, 0, 0);
      if (l == 0) {
#pragma unroll
        for (int c = 0; c < 4; ++c) {
          const float o = Co[c] + hob0;
          out[(size_t)s * NB + b0 + c] = o;
          av[c][0] = (f16)o;           // next step's prev; ordered by B1..B3 before p4
        }
      }
    }
  }
}

extern "C" void kernel_launch(void* const* d_in, const int* in_sizes, int n_in,
                              void* d_out, int out_size, void* d_ws, size_t ws_size,
                              hipStream_t stream)
{
  const float* ann   = (const float*)d_in[0];
  const float* xenc  = (const float*)d_in[1];
  const float* xdec  = (const float*)d_in[2];
  const float* W1    = (const float*)d_in[3];
  const float* b1    = (const float*)d_in[4];
  const float* W2    = (const float*)d_in[5];
  const float* b2    = (const float*)d_in[6];
  const float* eWih  = (const float*)d_in[7];
  const float* eWhh  = (const float*)d_in[8];
  const float* ebih  = (const float*)d_in[9];
  const float* ebhh  = (const float*)d_in[10];
  const float* dWih  = (const float*)d_in[11];
  const float* dWhh  = (const float*)d_in[12];
  const float* dbih  = (const float*)d_in[13];
  const float* dbhh  = (const float*)d_in[14];
  const float* UW    = (const float*)d_in[15];
  const float* Ubias = (const float*)d_in[16];
  const float* Wl    = (const float*)d_in[17];
  const float* Wlb   = (const float*)d_in[18];
  const float* Vw    = (const float*)d_in[19];
  const float* Vb    = (const float*)d_in[20];
  const float* how   = (const float*)d_in[21];
  const float* hob   = (const float*)d_in[22];

  char* ws = (char*)d_ws;
  float* hstate = (float*)(ws + OFF_H);
  f16*   encB   = (f16*)(ws + OFF_ENC);
  u16*   uoB    = (u16*)(ws + OFF_UO);
  const f16* pWenc = (const f16*)(ws + OFF_WENC);
  const f16* pWdec = (const f16*)(ws + OFF_WDEC);
  const f16* pWl   = (const f16*)(ws + OFF_WL);
  const f16* pUW   = (const f16*)(ws + OFF_UW);

  k_prep<<<200, 256, 0, stream>>>(eWih, eWhh, dWih, dWhh, UW, Wl, ws);
  k_mlp <<<128, 256, 0, stream>>>(ann, W1, b1, W2, b2, hstate);
  k_enc <<<NB / 8, 512, 0, stream>>>(xenc, pWenc, pUW, ebih, ebhh, Ubias,
                                     hstate, encB, uoB);
  k_dec <<<NB / 4, 768, 0, stream>>>(xdec, xenc, pWdec, pWl, dbih, dbhh,
                                     Wlb, Vw, Vb, how, hob, hstate,
                                     encB, uoB, (float*)d_out);
}

// Round 12
// 656.024 us; speedup vs baseline: 2.8320x; 1.7399x over previous
//
#include <hip/hip_runtime.h>
#include <stdint.h>

typedef unsigned int u32;
typedef unsigned short u16;
typedef _Float16 f16;
typedef _Float16 f16x8 __attribute__((ext_vector_type(8)));
typedef _Float16 f16x4 __attribute__((ext_vector_type(4)));
typedef _Float16 f16x2 __attribute__((ext_vector_type(2)));
typedef float f32x4 __attribute__((ext_vector_type(4)));

constexpr int NB = 4096;   // batch
constexpr int NT = 56;     // encoder steps
constexpr int NS = 28;     // decoder steps
constexpr int NH = 126;    // hidden
constexpr int NHP = 128;
constexpr float LOG2E = 1.4426950408889634f;

// decoder LDS row geometry: row 136 elems (%32 words = 4 -> per-t bank rotation)
constexpr int LROW = 136;
constexpr int LB   = NT * LROW + 8;   // 7624

// workspace offsets (bytes)
constexpr size_t OFF_H    = 0;                    // f32[4096*128] h state (pads 0)
constexpr size_t OFF_ENC  = 2097152;              // f16[4096*56*128] enc_out [b][t][h]
constexpr size_t OFF_UO   = OFF_ENC + 58720256;   // bf16[4096*56*128] EU=e^(2*Uo) [b][t][h]
constexpr size_t OFF_WENC = OFF_UO + 58720256;    // f16[384*160]  enc gates [x20+pad|h128]
constexpr size_t OFF_WDEC = OFF_WENC + 122880;    // f16[384*288]  dec gates [head16+pad|attn128|h128]
constexpr size_t OFF_WL   = OFF_WDEC + 221184;    // f16[128*128]  Wl
constexpr size_t OFF_UW   = OFF_WL + 32768;       // f16[128*128]  U_W

__device__ __forceinline__ float fexp2(float x){ return __builtin_amdgcn_exp2f(x); }
__device__ __forceinline__ float frcp (float x){ return __builtin_amdgcn_rcpf(x); }
__device__ __forceinline__ float sigm (float x){ return frcp(1.f + fexp2(-LOG2E * x)); }
__device__ __forceinline__ float ftanh(float x){ return 1.f - 2.f * frcp(1.f + fexp2(2.f * LOG2E * x)); }
__device__ __forceinline__ float asf(u32 u){ union { u32 i; float f; } v; v.i = u; return v.f; }
__device__ __forceinline__ u16 tobf(float f){ union { float f; u32 i; } v; v.f = f;
  return (u16)((v.i + 0x7fffu + ((v.i >> 16) & 1u)) >> 16); }

// ---------------- weight repack ----------------
__global__ void k_prep(const float* __restrict__ eWih, const float* __restrict__ eWhh,
                       const float* __restrict__ dWih, const float* __restrict__ dWhh,
                       const float* __restrict__ UW,   const float* __restrict__ Wl,
                       char* __restrict__ ws)
{
  f16* wenc = (f16*)(ws + OFF_WENC);
  f16* wdec = (f16*)(ws + OFF_WDEC);
  f16* wl   = (f16*)(ws + OFF_WL);
  f16* uw   = (f16*)(ws + OFF_UW);
  const int nE = 384 * 160, nD = 384 * 288, nW = 128 * 128;
  const int total = nE + nD + nW + nW;
  for (int i = blockIdx.x * 256 + threadIdx.x; i < total; i += gridDim.x * 256) {
    int idx = i;
    if (idx < nE) {
      const int r = idx / 160, c = idx % 160;
      float v = 0.f;
      if (r < 378) {
        if (c < 20) v = eWih[r * 20 + c];
        else if (c >= 32 && c < 158) v = eWhh[r * 126 + (c - 32)];
      }
      wenc[idx] = (f16)v; continue;
    }
    idx -= nE;
    if (idx < nD) {
      const int r = idx / 288, c = idx % 288;
      float v = 0.f;
      if (r < 378) {
        if (c < 16) v = dWih[r * 142 + c];
        else if (c >= 32 && c < 158) v = dWih[r * 142 + 16 + (c - 32)];
        else if (c >= 160 && c < 286) v = dWhh[r * 126 + (c - 160)];
      }
      wdec[idx] = (f16)v; continue;
    }
    idx -= nD;
    if (idx < nW) {
      const int r = idx >> 7, c = idx & 127;
      wl[idx] = (f16)((r < 126 && c < 126) ? Wl[r * 126 + c] : 0.f);
      continue;
    }
    idx -= nW;
    { const int r = idx >> 7, c = idx & 127;
      uw[idx] = (f16)((r < 126 && c < 126) ? UW[r * 126 + c] : 0.f); }
  }
}

// ---------------- init MLP ----------------
__global__ __launch_bounds__(256) void k_mlp(
    const float* __restrict__ ann, const float* __restrict__ W1, const float* __restrict__ b1,
    const float* __restrict__ W2, const float* __restrict__ b2, float* __restrict__ hstate)
{
  __shared__ float anns[32][33];
  __shared__ float t1s[32][101];
  const int tid = threadIdx.x;
  const int b0 = blockIdx.x * 32;
  for (int i = tid; i < 32 * 30; i += 256)
    anns[i / 30][i % 30] = ann[(b0 + i / 30) * 30 + (i % 30)];
  __syncthreads();
  const int b = tid & 31, rg = tid >> 5;
  for (int m = rg; m < 96; m += 8) {
    float a = b1[m];
    for (int k = 0; k < 30; ++k) a += W1[m * 30 + k] * anns[b][k];
    t1s[b][m] = fmaxf(a, 0.f);
  }
  __syncthreads();
  for (int j = rg; j < NHP; j += 8) {
    float a = 0.f;
    if (j < NH) {
      a = b2[j];
      for (int k = 0; k < 96; ++k) a += W2[j * 96 + k] * t1s[b][k];
    }
    hstate[(b0 + b) * NHP + j] = a;
  }
}

// ---------------- encoder: MFMA, reg-resident weights, M=16, h double-buffered ----------------
// Stores enc_out (f16) and EU = e^(2*Uo) (bf16).
__global__ __launch_bounds__(512) void k_enc(
    const float* __restrict__ xenc, const f16* __restrict__ Wenc,
    const f16* __restrict__ Uw,
    const float* __restrict__ bih, const float* __restrict__ bhh,
    const float* __restrict__ Ub,
    float* __restrict__ hstate, f16* __restrict__ encO, u16* __restrict__ uoO)
{
  __shared__ f16 av[16][296];   // [b][ x20+pad12 | h_p0 128 | h_p1 128 | pad ]
  const int tid = threadIdx.x;
  const int wid = tid >> 6, l = tid & 63, quad = l >> 4, col = l & 15;
  const int b0 = blockIdx.x * 16;
  const int jb = wid * 16, j = jb + col;
  const bool valid = j < NH;
  const int jc = valid ? j : NH - 1;

  const float br  = bih[jc]        + bhh[jc];
  const float bz  = bih[NH + jc]   + bhh[NH + jc];
  const float bnx = bih[2*NH + jc];
  const float bnh = bhh[2*NH + jc];
  const float ub  = Ub[jc];

  f16x8 rB[5], zB[5], nxB, nhB[4], uB[4];
  {
    const int ko = quad * 8, rr = jb + col;
#pragma unroll
    for (int kt = 0; kt < 5; ++kt) {
      rB[kt] = *(const f16x8*)&Wenc[rr * 160 + kt * 32 + ko];
      zB[kt] = *(const f16x8*)&Wenc[(NH + rr) * 160 + kt * 32 + ko];
    }
    nxB = *(const f16x8*)&Wenc[(2*NH + rr) * 160 + ko];
#pragma unroll
    for (int kt = 0; kt < 4; ++kt) {
      nhB[kt] = *(const f16x8*)&Wenc[(2*NH + rr) * 160 + 32 + kt * 32 + ko];
      uB[kt]  = *(const f16x8*)&Uw[rr * 128 + kt * 32 + ko];
    }
  }

  {
    const int bb = tid >> 5, c4 = (tid & 31) * 4;
    const float4 hv = *(const float4*)&hstate[(b0 + bb) * NHP + c4];
    av[bb][32 + c4]     = (f16)hv.x; av[bb][32 + c4 + 1] = (f16)hv.y;
    av[bb][32 + c4 + 2] = (f16)hv.z; av[bb][32 + c4 + 3] = (f16)hv.w;
  }
  if (tid < 192) { const int bb = tid / 12, p = tid % 12; av[bb][20 + p] = (f16)0.f; }
  __syncthreads();

  const int m = col, ko = quad * 8;
  for (int t = 0; t < NT; ++t) {
    const int hp = 32 + (t & 1) * 128, hq = 32 + ((t + 1) & 1) * 128;
    if (tid < 320) {
      const int bb = tid / 20, e = tid % 20;
      av[bb][e] = (f16)xenc[((size_t)t * NB + b0 + bb) * 20 + e];
    }
    __syncthreads();                       // B1
    f16x8 A[5];
    A[0] = *(const f16x8*)&av[m][ko];
#pragma unroll
    for (int kt = 1; kt < 5; ++kt) A[kt] = *(const f16x8*)&av[m][hp + (kt - 1) * 32 + ko];

    f32x4 Cr = {br, br, br, br}, Cz = {bz, bz, bz, bz};
    f32x4 Cnx = {bnx, bnx, bnx, bnx}, Cnh = {bnh, bnh, bnh, bnh};
#pragma unroll
    for (int kt = 0; kt < 5; ++kt) {
      Cr = __builtin_amdgcn_mfma_f32_16x16x32_f16(A[kt], rB[kt], Cr, 0, 0, 0);
      Cz = __builtin_amdgcn_mfma_f32_16x16x32_f16(A[kt], zB[kt], Cz, 0, 0, 0);
    }
    Cnx = __builtin_amdgcn_mfma_f32_16x16x32_f16(A[0], nxB, Cnx, 0, 0, 0);
#pragma unroll
    for (int kt = 0; kt < 4; ++kt)
      Cnh = __builtin_amdgcn_mfma_f32_16x16x32_f16(A[kt + 1], nhB[kt], Cnh, 0, 0, 0);

    float hv4[4];
#pragma unroll
    for (int c = 0; c < 4; ++c) {
      const int bb = quad * 4 + c;
      const float hold = (float)av[bb][hp + j];
      const float r = sigm(Cr[c]), z = sigm(Cz[c]);
      const float n = ftanh(Cnx[c] + r * Cnh[c]);
      hv4[c] = (1.f - z) * n + z * hold;
    }
#pragma unroll
    for (int c = 0; c < 4; ++c) {
      const int bb = quad * 4 + c;
      const f16 hs = valid ? (f16)hv4[c] : (f16)0.f;
      av[bb][hq + j] = hs;
      encO[((size_t)(b0 + bb) * NT + t) * 128 + j] = hs;
    }
    if (t == NT - 1 && valid) {
#pragma unroll
      for (int c = 0; c < 4; ++c)
        hstate[(b0 + quad * 4 + c) * NHP + j] = hv4[c];
    }
    __syncthreads();                       // B2

    f16x8 Ah[4];
#pragma unroll
    for (int kt = 0; kt < 4; ++kt) Ah[kt] = *(const f16x8*)&av[m][hq + kt * 32 + ko];
    f32x4 Cu = {ub, ub, ub, ub};
#pragma unroll
    for (int kt = 0; kt < 4; ++kt)
      Cu = __builtin_amdgcn_mfma_f32_16x16x32_f16(Ah[kt], uB[kt], Cu, 0, 0, 0);
#pragma unroll
    for (int c = 0; c < 4; ++c) {
      const u16 eu = tobf(fexp2(2.f * LOG2E * Cu[c]));   // EU = e^(2*Uo)
      uoO[((size_t)(b0 + quad * 4 + c) * NT + t) * 128 + j] = valid ? eu : (u16)0;
    }
  }
}

// ---------------- decoder: M=4, 512 threads (R9 structure), LDS-resident EU+enc ------------
// tanh(Uo+Wh)*V summed as svsum + sum(-2v * rcp(1 + EU*EW)); EW computed once per step.
__global__ __launch_bounds__(512) void k_dec(
    const float* __restrict__ xdec, const float* __restrict__ xenc,
    const f16* __restrict__ Wdec, const f16* __restrict__ WlW,
    const float* __restrict__ bih, const float* __restrict__ bhh,
    const float* __restrict__ Wlb, const float* __restrict__ Vw,
    const float* __restrict__ Vb, const float* __restrict__ how,
    const float* __restrict__ hob, const float* __restrict__ hstate,
    const f16* __restrict__ encO, const u16* __restrict__ uoO,
    float* __restrict__ out)
{
  __shared__ __align__(16) u16 uoL[4 * LB];      // EU bf16, 61.0 KB
  __shared__ __align__(16) f16 encL[4 * LB];     // 61.0 KB
  __shared__ __align__(16) f16 av[5][424];       // [b][head16+pad16|attn128|h_p0|h_p1|pad]; row4=0
  __shared__ float EWS[4][132];                  // e^(2*Wh)
  __shared__ float scS[4][68];
  __shared__ __align__(16) f16 hows16[128];
  const int tid = threadIdx.x;
  const int wid = tid >> 6, l = tid & 63, quad = l >> 4, col = l & 15;
  const int b0 = blockIdx.x * 4;
  const int jb = wid * 16, j = jb + col;
  const bool valid = j < NH;
  const int jc = valid ? j : NH - 1;

  const float br  = bih[jc]        + bhh[jc];
  const float bz  = bih[NH + jc]   + bhh[NH + jc];
  const float bnx = bih[2*NH + jc];
  const float bnh = bhh[2*NH + jc];
  const float wb  = Wlb[jc];
  const float vb0 = Vb[0], hob0 = hob[0];

  f16x8 rB[9], zB[9], nxB[5], nhB[4], wlB[4];
  {
    const int ko = quad * 8, rr = jb + col;
#pragma unroll
    for (int kt = 0; kt < 9; ++kt) {
      rB[kt] = *(const f16x8*)&Wdec[rr * 288 + kt * 32 + ko];
      zB[kt] = *(const f16x8*)&Wdec[(NH + rr) * 288 + kt * 32 + ko];
    }
#pragma unroll
    for (int kt = 0; kt < 5; ++kt)
      nxB[kt] = *(const f16x8*)&Wdec[(2*NH + rr) * 288 + kt * 32 + ko];
#pragma unroll
    for (int kt = 0; kt < 4; ++kt) {
      nhB[kt] = *(const f16x8*)&Wdec[(2*NH + rr) * 288 + 160 + kt * 32 + ko];
      wlB[kt] = *(const f16x8*)&WlW[rr * 128 + kt * 32 + ko];
    }
  }

  const int g = tid >> 3, sub = tid & 7;
  float n2v[16], svsum = 0.f;
#pragma unroll
  for (int i = 0; i < 16; ++i) {
    const int jj = sub * 16 + i;
    const float v = (jj < NH) ? Vw[jj] : 0.f;
    n2v[i] = -2.f * v;
    svsum += v;
  }
  if (tid >= 256 && tid < 384) {
    const int q = tid - 256; hows16[q] = (f16)((q < NH) ? how[q] : 0.f);
  }
  for (int i = tid; i < 5 * 424; i += 512) av[i / 424][i % 424] = (f16)0.f;
  if (tid < 24) EWS[tid / 6][126 + tid % 6] = 0.f;   // pad cols stay 0 (avoid NaN)
  {
    const size_t gb = (size_t)b0 * NT * 128;
    for (int i = tid; i < 4 * NT * 16; i += 512) {
      const int ch = i & 15, btr = i >> 4;
      const int bb = btr / NT, tt = btr % NT;
      const int dst = bb * LB + tt * LROW + ch * 8;
      const size_t src = gb + (size_t)btr * 128 + ch * 8;
      *(f16x8*)&uoL [dst] = *(const f16x8*)&uoO [src];
      *(f16x8*)&encL[dst] = *(const f16x8*)&encO[src];
    }
  }
  __syncthreads();
  if (tid < 128) {   // h0 rows 0..3 into parity-0 [160..288)
    const int bb = tid >> 5, c4 = (tid & 31) * 4;
    const float4 hv = *(const float4*)&hstate[(b0 + bb) * NHP + c4];
    av[bb][160 + c4]     = (f16)hv.x; av[bb][160 + c4 + 1] = (f16)hv.y;
    av[bb][160 + c4 + 2] = (f16)hv.z; av[bb][160 + c4 + 3] = (f16)hv.w;
  }
  if (tid < 4) av[tid][0] = (f16)xenc[((size_t)(NT - 1) * NB + b0 + tid) * 20];  // gt0
  __syncthreads();

  const int m = col, ko = quad * 8;
  const int arow = (m < 4) ? m : 4;
  const int pb = tid & 3, pth = (tid >> 2) & 1, pjp = tid >> 3;   // p3 map

  for (int s = 0; s < NS; ++s) {
    const int hp = 160 + (s & 1) * 128, hq = 160 + ((s + 1) & 1) * 128;

    // p1: Wh -> EW = e^(2*Wh) (MFMA); stage dec_x
    {
      f16x8 Ah[4];
#pragma unroll
      for (int kt = 0; kt < 4; ++kt) Ah[kt] = *(const f16x8*)&av[arow][hp + kt * 32 + ko];
      f32x4 Cw = {wb, wb, wb, wb};
#pragma unroll
      for (int kt = 0; kt < 4; ++kt)
        Cw = __builtin_amdgcn_mfma_f32_16x16x32_f16(Ah[kt], wlB[kt], Cw, 0, 0, 0);
      if (quad == 0 && valid) {
#pragma unroll
        for (int c = 0; c < 4; ++c) EWS[c][j] = fexp2(2.f * LOG2E * Cw[c]);
      }
    }
    if (tid < 60) { const int bb = tid / 15, e = tid % 15;
      av[bb][1 + e] = (f16)xdec[((size_t)s * NB + b0 + bb) * 15 + e]; }
    __syncthreads();  // B1

    // p2: scores via svsum + sum(-2v/(1+EU*EW)); 64 groups = 4b x 16 t-base, 4 rounds
    {
      const int sbb = g & 3, tb = g >> 2;
      float ew[16];
#pragma unroll
      for (int i = 0; i < 4; ++i)
        *(float4*)&ew[i * 4] = *(const float4*)&EWS[sbb][sub * 16 + i * 4];
      const u16* up0 = &uoL[sbb * LB + sub * 16];
#pragma unroll
      for (int rd = 0; rd < 4; ++rd) {
        const int t = rd * 16 + tb;
        if (t < NT) {
          const u16* up = up0 + t * LROW;
          const uint4 q0 = *(const uint4*)&up[0];
          const uint4 q1 = *(const uint4*)&up[8];
          float acc = svsum;
          const u32 wsv[8] = {q0.x, q0.y, q0.z, q0.w, q1.x, q1.y, q1.z, q1.w};
#pragma unroll
          for (int k = 0; k < 8; ++k) {
            const float p0 = fmaf(asf(wsv[k] << 16),         ew[2 * k],     1.f);
            const float p1 = fmaf(asf(wsv[k] & 0xffff0000u), ew[2 * k + 1], 1.f);
            acc = fmaf(n2v[2 * k],     frcp(p0), acc);
            acc = fmaf(n2v[2 * k + 1], frcp(p1), acc);
          }
          acc += __shfl_xor(acc, 1, 64);
          acc += __shfl_xor(acc, 2, 64);
          acc += __shfl_xor(acc, 4, 64);
          if (sub == 0) scS[sbb][t] = acc + vb0;
        }
      }
    }
    __syncthreads();  // B2

    // p3: fused softmax + attn (all 512 threads); scores bounded -> no max subtraction
    {
      const int j0 = pjp * 2;
      const f16* er = &encL[pb * LB + j0];
      const float* scp = &scS[pb][pth * 28];
      const int tbase = pth * 28;
      float Z = 0.f, a0 = 0.f, a1 = 0.f;
#pragma unroll
      for (int i2 = 0; i2 < 28; i2 += 2) {
        const float2 scv = *(const float2*)&scp[i2];
        const float e0 = fexp2(LOG2E * scv.x);
        const float e1 = fexp2(LOG2E * scv.y);
        Z += e0 + e1;
        const f16x2 v0 = *(const f16x2*)&er[(tbase + i2    ) * LROW];
        const f16x2 v1 = *(const f16x2*)&er[(tbase + i2 + 1) * LROW];
        a0 += e0 * (float)v0[0] + e1 * (float)v1[0];
        a1 += e0 * (float)v0[1] + e1 * (float)v1[1];
      }
      a0 += __shfl_xor(a0, 4, 64);
      a1 += __shfl_xor(a1, 4, 64);
      Z  += __shfl_xor(Z, 4, 64);
      if (pth == 0) {
        const float inv = frcp(Z);
        f16x2 st; st[0] = (f16)(a0 * inv); st[1] = (f16)(a1 * inv);
        *(f16x2*)&av[pb][32 + j0] = st;
      }
    }
    __syncthreads();  // B3

    // p4: GRU gates (MFMA) + state update into other parity
    {
      f16x8 A[9];
#pragma unroll
      for (int kt = 0; kt < 5; ++kt) A[kt] = *(const f16x8*)&av[arow][kt * 32 + ko];
#pragma unroll
      for (int kt = 5; kt < 9; ++kt) A[kt] = *(const f16x8*)&av[arow][hp + (kt - 5) * 32 + ko];
      f32x4 Cr = {br, br, br, br}, Cz = {bz, bz, bz, bz};
      f32x4 Cnx = {bnx, bnx, bnx, bnx}, Cnh = {bnh, bnh, bnh, bnh};
#pragma unroll
      for (int kt = 0; kt < 9; ++kt) {
        Cr = __builtin_amdgcn_mfma_f32_16x16x32_f16(A[kt], rB[kt], Cr, 0, 0, 0);
        Cz = __builtin_amdgcn_mfma_f32_16x16x32_f16(A[kt], zB[kt], Cz, 0, 0, 0);
      }
#pragma unroll
      for (int kt = 0; kt < 5; ++kt)
        Cnx = __builtin_amdgcn_mfma_f32_16x16x32_f16(A[kt], nxB[kt], Cnx, 0, 0, 0);
#pragma unroll
      for (int kt = 0; kt < 4; ++kt)
        Cnh = __builtin_amdgcn_mfma_f32_16x16x32_f16(A[kt + 5], nhB[kt], Cnh, 0, 0, 0);
      if (quad == 0) {
#pragma unroll
        for (int c = 0; c < 4; ++c) {
          const float hold = (float)av[c][hp + j];
          const float r = sigm(Cr[c]), z = sigm(Cz[c]);
          const float n = ftanh(Cnx[c] + r * Cnh[c]);
          const float h2 = (1.f - z) * n + z * hold;
          if (valid) av[c][hq + j] = (f16)h2;
        }
      }
    }
    __syncthreads();  // B4

    // p5: out = h' . h2o + b via n=1 MFMA on wave 0
    if (wid == 0) {
      f16x8 Ah2[4], hB[4];
      const f16x8 zz = {};
#pragma unroll
      for (int kt = 0; kt < 4; ++kt) {
        Ah2[kt] = *(const f16x8*)&av[arow][hq + kt * 32 + ko];
        hB[kt] = (col == 0) ? *(const f16x8*)&hows16[kt * 32 + ko] : zz;
      }
      f32x4 Co = {0.f, 0.f, 0.f, 0.f};
#pragma unroll
      for (int kt = 0; kt < 4; ++kt)
        Co = __builtin_amdgcn_mfma_f32_16x16x32_f16(Ah2[kt], hB[kt], Co, 0, 0, 0);
      if (l == 0) {
#pragma unroll
        for (int c = 0; c < 4; ++c) {
          const float o = Co[c] + hob0;
          out[(size_t)s * NB + b0 + c] = o;
          av[c][0] = (f16)o;           // next step's prev; ordered by B1..B3 before p4
        }
      }
    }
  }
}

extern "C" void kernel_launch(void* const* d_in, const int* in_sizes, int n_in,
                              void* d_out, int out_size, void* d_ws, size_t ws_size,
                              hipStream_t stream)
{
  const float* ann   = (const float*)d_in[0];
  const float* xenc  = (const float*)d_in[1];
  const float* xdec  = (const float*)d_in[2];
  const float* W1    = (const float*)d_in[3];
  const float* b1    = (const float*)d_in[4];
  const float* W2    = (const float*)d_in[5];
  const float* b2    = (const float*)d_in[6];
  const float* eWih  = (const float*)d_in[7];
  const float* eWhh  = (const float*)d_in[8];
  const float* ebih  = (const float*)d_in[9];
  const float* ebhh  = (const float*)d_in[10];
  const float* dWih  = (const float*)d_in[11];
  const float* dWhh  = (const float*)d_in[12];
  const float* dbih  = (const float*)d_in[13];
  const float* dbhh  = (const float*)d_in[14];
  const float* UW    = (const float*)d_in[15];
  const float* Ubias = (const float*)d_in[16];
  const float* Wl    = (const float*)d_in[17];
  const float* Wlb   = (const float*)d_in[18];
  const float* Vw    = (const float*)d_in[19];
  const float* Vb    = (const float*)d_in[20];
  const float* how   = (const float*)d_in[21];
  const float* hob   = (const float*)d_in[22];

  char* ws = (char*)d_ws;
  float* hstate = (float*)(ws + OFF_H);
  f16*   encB   = (f16*)(ws + OFF_ENC);
  u16*   uoB    = (u16*)(ws + OFF_UO);
  const f16* pWenc = (const f16*)(ws + OFF_WENC);
  const f16* pWdec = (const f16*)(ws + OFF_WDEC);
  const f16* pWl   = (const f16*)(ws + OFF_WL);
  const f16* pUW   = (const f16*)(ws + OFF_UW);

  k_prep<<<200, 256, 0, stream>>>(eWih, eWhh, dWih, dWhh, UW, Wl, ws);
  k_mlp <<<128, 256, 0, stream>>>(ann, W1, b1, W2, b2, hstate);
  k_enc <<<NB / 16, 512, 0, stream>>>(xenc, pWenc, pUW, ebih, ebhh, Ubias,
                                      hstate, encB, uoB);
  k_dec <<<NB / 4, 512, 0, stream>>>(xdec, xenc, pWdec, pWl, dbih, dbhh,
                                     Wlb, Vw, Vb, how, hob, hstate,
                                     encB, uoB, (float*)d_out);
}